// Round 10
// baseline (76.084 us; speedup 1.0000x reference)
//
#include <hip/hip_runtime.h>
#include <hip/hip_bf16.h>

#define TT 2048
#define HH 1024
#define NTAGS 74
#define NPAD 80
#define MROWS 32          // rows per block
#define THREADS 512

typedef __bf16 bf16x8 __attribute__((ext_vector_type(8)));
typedef float f32x4 __attribute__((ext_vector_type(4)));

// Transpose + convert W_out [1024][74] f32 -> Wt [80][1024] bf16 (pad cols 74..79 = 0)
__global__ __launch_bounds__(256) void prep_w_kernel(const float* __restrict__ W,
                                                     __bf16* __restrict__ Wt) {
    __shared__ float tile[64][80];
    const int k0 = blockIdx.x * 64;
    const int tid = threadIdx.x;
    for (int i = tid; i < 64 * NTAGS; i += 256) {
        int k = i / NTAGS, n = i - k * NTAGS;
        tile[k][n] = W[(k0 + k) * NTAGS + n];
    }
    __syncthreads();
    for (int i = tid; i < NPAD * 64; i += 256) {
        int n = i >> 6, kk = i & 63;
        float v = (n < NTAGS) ? tile[kk][n] : 0.0f;
        Wt[n * HH + k0 + kk] = (__bf16)v;
    }
}

// R10: 3-barrier structure. Block = 512 thr (8 waves), M=32 rows, grid 1024.
// Wave w: rowgroup g=w>>2 (16 rows), K-slice kq=w&3 (256 k). W fragments live
// in REGISTERS (5 nt x 8 ch = 40 bf16x8 = 80 VGPR per wave) -> zero W LDS
// traffic. A staged ONCE full-K: [32][1024] bf16 = 64 KB, XOR-swizzled
// (byte ^= (row&7)<<4), one unbarriered burst of 32 float4/thread/input.
// Then: barrier -> 40 MFMA (A-frags via 8 ds_read_b128) -> barrier ->
// split-K x4 LDS reduction (reuses A space) -> store. Early-exit for
// fully-invalid blocks. ~450 instrs/wave vs ~1800 in the chunked pipeline.
__global__ __launch_bounds__(512, 1) void slu_main(const float* __restrict__ out_char,
                                                   const float* __restrict__ out_word,
                                                   const int* __restrict__ word_idx,
                                                   const int* __restrict__ is_head,
                                                   const int* __restrict__ valid_mask,
                                                   const __bf16* __restrict__ Wt,
                                                   const float* __restrict__ b_out,
                                                   float* __restrict__ out) {
    __shared__ __align__(16) char smem[65536];  // A[32][2048B]; reduce reuses 40 KB
    const int tid = threadIdx.x;
    const int wv = tid >> 6;      // 0..7
    const int lane = tid & 63;
    const int l15 = lane & 15;
    const int kgrp = lane >> 4;   // 0..3
    const int rowbase = blockIdx.x * MROWS;
    const int batch = rowbase >> 11;  // T = 2048
    const size_t batbase = (size_t)batch * TT;

    // ---- early-exit: fully-invalid block writes bias and returns ----
    const int myv = (tid < MROWS) ? valid_mask[rowbase + tid] : 0;
    if (!__syncthreads_or(myv)) {
        for (int i = tid; i < MROWS * NTAGS; i += THREADS) {
            const int rr = i / NTAGS, cc = i - rr * NTAGS;
            out[(size_t)(rowbase + rr) * NTAGS + cc] = b_out[cc];
        }
        return;
    }

    // ---- W fragments in registers: wave (g = wv>>2, kq = wv&3) ----
    const int g = wv >> 2, kq = wv & 3;
    bf16x8 wf[5][8];
#pragma unroll
    for (int nt = 0; nt < 5; ++nt) {
        const __bf16* wrow = Wt + (size_t)(nt * 16 + l15) * HH + kq * 256 + kgrp * 8;
#pragma unroll
        for (int ch = 0; ch < 8; ++ch) {
            wf[nt][ch] = *(const bf16x8*)(wrow + ch * 32);
        }
    }

    // ---- A staging: thread covers row srow=tid>>4, 16-f32 strip su=tid&15 ----
    const int srow = tid >> 4;    // 0..31
    const int su = tid & 15;
    const int r = rowbase + srow;
    const int val = valid_mask[r];
    const float rt = is_head[r] ? 0.88f : 0.70f;
    const float rate = val ? rt : 0.0f;
    const float crate = val ? (1.0f - rt) : 0.0f;
    const float* cptr = out_char + (size_t)r * HH;
    const float* wptr = out_word + (batbase + word_idx[r]) * HH;
    const int s7 = (srow & 7) << 4;
    char* arow_base = smem + srow * 2048;

    // 4 rounds x (4 char f4 + 4 word f4 -> blend -> 2 ds_write_b128); no barriers
#pragma unroll
    for (int r4 = 0; r4 < 4; ++r4) {
        const int k0 = r4 * 256 + su * 16;
        float4 c[4], w[4];
        if (val) {
#pragma unroll
            for (int i = 0; i < 4; ++i) {
                c[i] = *(const float4*)(cptr + k0 + i * 4);
                w[i] = *(const float4*)(wptr + k0 + i * 4);
            }
        }
        bf16x8 f0, f1;
        if (val) {
#pragma unroll
            for (int i = 0; i < 2; ++i) {
                f0[i * 4 + 0] = (__bf16)(w[i].x * rate + c[i].x * crate);
                f0[i * 4 + 1] = (__bf16)(w[i].y * rate + c[i].y * crate);
                f0[i * 4 + 2] = (__bf16)(w[i].z * rate + c[i].z * crate);
                f0[i * 4 + 3] = (__bf16)(w[i].w * rate + c[i].w * crate);
                f1[i * 4 + 0] = (__bf16)(w[i + 2].x * rate + c[i + 2].x * crate);
                f1[i * 4 + 1] = (__bf16)(w[i + 2].y * rate + c[i + 2].y * crate);
                f1[i * 4 + 2] = (__bf16)(w[i + 2].z * rate + c[i + 2].z * crate);
                f1[i * 4 + 3] = (__bf16)(w[i + 2].w * rate + c[i + 2].w * crate);
            }
        } else {
            f0 = (bf16x8)0; f1 = (bf16x8)0;
        }
        const int kb = r4 * 512 + su * 32;
        *(bf16x8*)(arow_base + ((kb) ^ s7)) = f0;
        *(bf16x8*)(arow_base + ((kb + 16) ^ s7)) = f1;
    }
    __syncthreads();

    // ---- compute: 8 A-frag ds_reads + 40 MFMA (W from regs) ----
    f32x4 acc[5];
#pragma unroll
    for (int nt = 0; nt < 5; ++nt) acc[nt] = (f32x4){0.f, 0.f, 0.f, 0.f};
    const int arow = g * 16 + l15;
    const char* abase = smem + arow * 2048;
    const int asw = (l15 & 7) << 4;   // arow&7 == l15&7
#pragma unroll
    for (int ch = 0; ch < 8; ++ch) {
        bf16x8 a = *(const bf16x8*)(abase + ((kq * 512 + ch * 64 + kgrp * 16) ^ asw));
#pragma unroll
        for (int nt = 0; nt < 5; ++nt) {
            acc[nt] = __builtin_amdgcn_mfma_f32_16x16x32_bf16(a, wf[nt][ch], acc[nt], 0, 0, 0);
        }
    }
    __syncthreads();

    // ---- split-K x4 reduction via LDS (reuses A space; 8x5x64x16B = 40 KB) ----
    f32x4* part = (f32x4*)smem;
#pragma unroll
    for (int nt = 0; nt < 5; ++nt) part[(wv * 5 + nt) * 64 + lane] = acc[nt];
    __syncthreads();

    // 10 units (g_, nt_): wave wv handles unit wv; waves 0,1 also units 8,9.
#pragma unroll
    for (int e = 0; e < 2; ++e) {
        const int u = wv + e * 8;
        if (u < 10) {
            const int g_ = u / 5, nt_ = u - g_ * 5;
            f32x4 s = part[((g_ * 4 + 0) * 5 + nt_) * 64 + lane];
#pragma unroll
            for (int k = 1; k < 4; ++k) s += part[((g_ * 4 + k) * 5 + nt_) * 64 + lane];
            const int col = nt_ * 16 + l15;
            if (col < NTAGS) {
                const float bias = b_out[col];
                const int orow = rowbase + g_ * 16 + kgrp * 4;
#pragma unroll
                for (int i = 0; i < 4; ++i) {
                    out[(size_t)(orow + i) * NTAGS + col] = s[i] + bias;
                }
            }
        }
    }
}

extern "C" void kernel_launch(void* const* d_in, const int* in_sizes, int n_in,
                              void* d_out, int out_size, void* d_ws, size_t ws_size,
                              hipStream_t stream) {
    const float* out_char = (const float*)d_in[0];
    const float* out_word = (const float*)d_in[1];
    const int* word_idx = (const int*)d_in[2];
    const int* is_head = (const int*)d_in[3];
    const int* valid_mask = (const int*)d_in[4];
    const float* W_out = (const float*)d_in[5];
    const float* b_out = (const float*)d_in[6];
    float* out = (float*)d_out;
    __bf16* Wt = (__bf16*)d_ws;  // 80*1024*2 = 160 KB

    prep_w_kernel<<<HH / 64, 256, 0, stream>>>(W_out, Wt);

    const int rows = 16 * TT;  // B*T = 32768
    slu_main<<<rows / MROWS, THREADS, 0, stream>>>(out_char, out_word, word_idx, is_head,
                                                   valid_mask, Wt, b_out, out);
}

// Round 11
// 35.886 us; speedup vs baseline: 2.1202x; 2.1202x over previous
//
#include <hip/hip_runtime.h>
#include <hip/hip_bf16.h>

#define TT 2048
#define HH 1024
#define NTAGS 74
#define NPAD 80
#define CHK 32            // K elems per chunk (per half)
#define NPH 16            // phases; per wave K = NPH*CHK = 512
#define MROWS 64          // rows per block
#define THREADS 512

typedef __bf16 bf16x8 __attribute__((ext_vector_type(8)));
typedef float f32x4 __attribute__((ext_vector_type(4)));

// Transpose + convert W_out [1024][74] f32 -> Wt [80][1024] bf16 (pad cols 74..79 = 0)
__global__ __launch_bounds__(256) void prep_w_kernel(const float* __restrict__ W,
                                                     __bf16* __restrict__ Wt) {
    __shared__ float tile[64][80];
    const int k0 = blockIdx.x * 64;
    const int tid = threadIdx.x;
    for (int i = tid; i < 64 * NTAGS; i += 256) {
        int k = i / NTAGS, n = i - k * NTAGS;
        tile[k][n] = W[(k0 + k) * NTAGS + n];
    }
    __syncthreads();
    for (int i = tid; i < NPAD * 64; i += 256) {
        int n = i >> 6, kk = i & 63;
        float v = (n < NTAGS) ? tile[kk][n] : 0.0f;
        Wt[n * HH + k0 + kk] = (__bf16)v;
    }
}

// R11 = R5 tile + doubled TLP. 512 thr (8 waves), M=64, grid 512 -> 16 waves/CU.
// Split-K x2: wave wv -> (sw=wv>>1 rows sw*16.., h=wv&1 K-half). Per phase both
// halves stage their CHK=32 chunk (threads 0-255: half0 A, 256-511: half1 A),
// 5 MFMA/wave/phase. LDS stride-80B pad (conflict-free, no XOR):
// A[h][buf] @ (h*2+buf)*5120, W[h][buf] @ 20480+(h*2+buf)*6400 = 46080 B.
// Pipeline per R5: commit regs(ph+1) -> load regs(ph+2) -> MFMA(ph) -> barrier.
// Split-K x2 LDS reduction at end; fully-invalid blocks early-exit with bias.
__global__ __launch_bounds__(512, 4) void slu_main(const float* __restrict__ out_char,
                                                   const float* __restrict__ out_word,
                                                   const int* __restrict__ word_idx,
                                                   const int* __restrict__ is_head,
                                                   const int* __restrict__ valid_mask,
                                                   const __bf16* __restrict__ Wt,
                                                   const float* __restrict__ b_out,
                                                   float* __restrict__ out) {
    __shared__ __align__(16) char smem[46080];
    const int tid = threadIdx.x;
    const int wv = tid >> 6;      // 0..7
    const int lane = tid & 63;
    const int l15 = lane & 15;
    const int kgrp = lane >> 4;
    const int rowbase = blockIdx.x * MROWS;
    const int batch = rowbase >> 11;  // T = 2048
    const size_t batbase = (size_t)batch * TT;

    // ---- early-exit: fully-invalid block writes bias and returns ----
    const int myv = (tid < MROWS) ? valid_mask[rowbase + tid] : 0;
    if (!__syncthreads_or(myv)) {
        for (int i = tid; i < MROWS * NTAGS; i += THREADS) {
            const int rr = i / NTAGS, cc = i - rr * NTAGS;
            out[(size_t)(rowbase + rr) * NTAGS + cc] = b_out[cc];
        }
        return;
    }

    // ---- A staging: thread half hA covers row srow=(tid&255)>>2, 32B strip su ----
    const int hA = tid >> 8;          // which K-half this thread stages
    const int t8 = tid & 255;
    const int srow = t8 >> 2;         // 0..63
    const int su = t8 & 3;            // 8-f32 strip within chunk
    const int r = rowbase + srow;
    const int widx = word_idx[r];
    const int val = valid_mask[r];
    const float rt = is_head[r] ? 0.88f : 0.70f;
    const float rate = val ? rt : 0.0f;
    const float crate = val ? (1.0f - rt) : 0.0f;
    const float* cptr = out_char + (size_t)r * HH + hA * 512 + su * 8;
    const float* wptr = out_word + (batbase + widx) * HH + hA * 512 + su * 8;
    const int awr = srow * 80 + su * 16;  // + A base(hA, buf)

    // ---- W staging: 640 16B-units (2 halves x 80 rows x 4) ----
    const int u0 = tid;
    const int h0 = (u0 >= 320) ? 1 : 0;
    const int v0 = u0 - h0 * 320;
    const int n0 = v0 >> 2, uu0 = v0 & 3;
    const __bf16* wtp0 = Wt + (size_t)n0 * HH + h0 * 512 + uu0 * 8;
    const int wwr0 = n0 * 80 + uu0 * 16;  // + W base(h0, buf)
    const bool w2 = (tid < 128);
    const int v1 = 192 + tid;             // unit 512+tid -> half1, v=192..319
    const int n1 = v1 >> 2, uu1 = v1 & 3;
    const __bf16* wtp1 = Wt + (size_t)n1 * HH + 512 + uu1 * 8;
    const int wwr1 = n1 * 80 + uu1 * 16;  // + W base(1, buf)

    // ---- fragment offsets: wave (sw, hh) ----
    const int sw = wv >> 1, hh = wv & 1;
    const int aoff = (sw * 16 + l15) * 80 + kgrp * 16;
    int woff[5];
#pragma unroll
    for (int nt = 0; nt < 5; ++nt) woff[nt] = (nt * 16 + l15) * 80 + kgrp * 16;

#define ABASE(h, b) (((h) * 2 + (b)) * 5120)
#define WBASE(h, b) (20480 + ((h) * 2 + (b)) * 6400)

    f32x4 acc[5];
#pragma unroll
    for (int nt = 0; nt < 5; ++nt) acc[nt] = (f32x4){0.f, 0.f, 0.f, 0.f};

    float4 hc0, hc1, hw0, hw1;   // held A loads (next-next phase)
    bf16x8 hwt0, hwt1;

    // ---- prologue: stage ph0 direct; load ph1 into regs ----
    {
        float4 c0, c1, w0, w1;
        if (val) {
            c0 = *(const float4*)(cptr);
            c1 = *(const float4*)(cptr + 4);
            w0 = *(const float4*)(wptr);
            w1 = *(const float4*)(wptr + 4);
        }
        bf16x8 t0 = *(const bf16x8*)(wtp0);
        bf16x8 t1 = w2 ? *(const bf16x8*)(wtp1) : (bf16x8)0;
        bf16x8 f;
        if (val) {
            f[0] = (__bf16)(w0.x * rate + c0.x * crate);
            f[1] = (__bf16)(w0.y * rate + c0.y * crate);
            f[2] = (__bf16)(w0.z * rate + c0.z * crate);
            f[3] = (__bf16)(w0.w * rate + c0.w * crate);
            f[4] = (__bf16)(w1.x * rate + c1.x * crate);
            f[5] = (__bf16)(w1.y * rate + c1.y * crate);
            f[6] = (__bf16)(w1.z * rate + c1.z * crate);
            f[7] = (__bf16)(w1.w * rate + c1.w * crate);
        } else {
            f = (bf16x8)0;
        }
        *(bf16x8*)(smem + ABASE(hA, 0) + awr) = f;
        *(bf16x8*)(smem + WBASE(h0, 0) + wwr0) = t0;
        if (w2) *(bf16x8*)(smem + WBASE(1, 0) + wwr1) = t1;
        // load ph1
        if (val) {
            hc0 = *(const float4*)(cptr + CHK);
            hc1 = *(const float4*)(cptr + CHK + 4);
            hw0 = *(const float4*)(wptr + CHK);
            hw1 = *(const float4*)(wptr + CHK + 4);
        }
        hwt0 = *(const bf16x8*)(wtp0 + CHK);
        hwt1 = w2 ? *(const bf16x8*)(wtp1 + CHK) : (bf16x8)0;
    }
    __syncthreads();

    // ---- main loop ----
    for (int ph = 0; ph < NPH; ++ph) {
        // 1) commit held phase ph+1 to buffer (ph+1)&1
        if (ph + 1 < NPH) {
            const int b = (ph + 1) & 1;
            bf16x8 f;
            if (val) {
                f[0] = (__bf16)(hw0.x * rate + hc0.x * crate);
                f[1] = (__bf16)(hw0.y * rate + hc0.y * crate);
                f[2] = (__bf16)(hw0.z * rate + hc0.z * crate);
                f[3] = (__bf16)(hw0.w * rate + hc0.w * crate);
                f[4] = (__bf16)(hw1.x * rate + hc1.x * crate);
                f[5] = (__bf16)(hw1.y * rate + hc1.y * crate);
                f[6] = (__bf16)(hw1.z * rate + hc1.z * crate);
                f[7] = (__bf16)(hw1.w * rate + hc1.w * crate);
            } else {
                f = (bf16x8)0;
            }
            *(bf16x8*)(smem + ABASE(hA, b) + awr) = f;
            *(bf16x8*)(smem + WBASE(h0, b) + wwr0) = hwt0;
            if (w2) *(bf16x8*)(smem + WBASE(1, b) + wwr1) = hwt1;
        }
        // 2) issue loads for phase ph+2
        if (ph + 2 < NPH) {
            const int kc = (ph + 2) * CHK;
            if (val) {
                hc0 = *(const float4*)(cptr + kc);
                hc1 = *(const float4*)(cptr + kc + 4);
                hw0 = *(const float4*)(wptr + kc);
                hw1 = *(const float4*)(wptr + kc + 4);
            }
            hwt0 = *(const bf16x8*)(wtp0 + kc);
            hwt1 = w2 ? *(const bf16x8*)(wtp1 + kc) : (bf16x8)0;
        }
        // 3) compute phase ph from buffer ph&1 of this wave's half
        const char* Ab = smem + ABASE(hh, ph & 1);
        const char* Wb = smem + WBASE(hh, ph & 1);
        bf16x8 a = *(const bf16x8*)(Ab + aoff);
#pragma unroll
        for (int nt = 0; nt < 5; ++nt) {
            bf16x8 bw = *(const bf16x8*)(Wb + woff[nt]);
            acc[nt] = __builtin_amdgcn_mfma_f32_16x16x32_bf16(a, bw, acc[nt], 0, 0, 0);
        }
        __syncthreads();
    }

    // ---- split-K x2 reduction via LDS (40 KB, reuses smem; loop ended with barrier) ----
    f32x4* part = (f32x4*)smem;
#pragma unroll
    for (int nt = 0; nt < 5; ++nt) part[(wv * 5 + nt) * 64 + lane] = acc[nt];
    __syncthreads();

    // 20 units (sw_, nt_); wave wv handles u = wv, wv+8, wv+16(<20)
#pragma unroll
    for (int e = 0; e < 3; ++e) {
        const int u = wv + e * 8;
        if (u < 20) {
            const int swu = u / 5, nt_ = u - swu * 5;
            f32x4 s = part[((2 * swu) * 5 + nt_) * 64 + lane];
            s += part[((2 * swu + 1) * 5 + nt_) * 64 + lane];
            const int col = nt_ * 16 + l15;
            if (col < NTAGS) {
                const float bias = b_out[col];
                const int orow = rowbase + swu * 16 + kgrp * 4;
#pragma unroll
                for (int i = 0; i < 4; ++i) {
                    out[(size_t)(orow + i) * NTAGS + col] = s[i] + bias;
                }
            }
        }
    }
#undef ABASE
#undef WBASE
}

extern "C" void kernel_launch(void* const* d_in, const int* in_sizes, int n_in,
                              void* d_out, int out_size, void* d_ws, size_t ws_size,
                              hipStream_t stream) {
    const float* out_char = (const float*)d_in[0];
    const float* out_word = (const float*)d_in[1];
    const int* word_idx = (const int*)d_in[2];
    const int* is_head = (const int*)d_in[3];
    const int* valid_mask = (const int*)d_in[4];
    const float* W_out = (const float*)d_in[5];
    const float* b_out = (const float*)d_in[6];
    float* out = (float*)d_out;
    __bf16* Wt = (__bf16*)d_ws;  // 80*1024*2 = 160 KB

    prep_w_kernel<<<HH / 64, 256, 0, stream>>>(W_out, Wt);

    const int rows = 16 * TT;  // B*T = 32768
    slu_main<<<rows / MROWS, THREADS, 0, stream>>>(out_char, out_word, word_idx, is_head,
                                                   valid_mask, Wt, b_out, out);
}

// Round 12
// 35.048 us; speedup vs baseline: 2.1709x; 1.0239x over previous
//
#include <hip/hip_runtime.h>
#include <hip/hip_bf16.h>

#define TT 2048
#define HH 1024
#define NTAGS 74
#define NPAD 80
#define CHK 64            // K elements per chunk
#define NCH (HH / CHK)    // 16 chunks
#define MROWS 64          // rows per block
#define THREADS 256
#define NXCD 8

typedef __bf16 bf16x8 __attribute__((ext_vector_type(8)));
typedef float f32x4 __attribute__((ext_vector_type(4)));

// Transpose + convert W_out [1024][74] f32 -> Wt [80][1024] bf16 (pad cols 74..79 = 0)
__global__ __launch_bounds__(256) void prep_w_kernel(const float* __restrict__ W,
                                                     __bf16* __restrict__ Wt) {
    __shared__ float tile[64][80];
    const int k0 = blockIdx.x * 64;
    const int tid = threadIdx.x;
    for (int i = tid; i < 64 * NTAGS; i += 256) {
        int k = i / NTAGS, n = i - k * NTAGS;
        tile[k][n] = W[(k0 + k) * NTAGS + n];
    }
    __syncthreads();
    for (int i = tid; i < NPAD * 64; i += 256) {
        int n = i >> 6, kk = i & 63;
        float v = (n < NTAGS) ? tile[kk][n] : 0.0f;
        Wt[n * HH + k0 + kk] = (__bf16)v;
    }
}

// R12 = R5 (best known: 35.5 us) + ONE change: bijective XCD-aware blockIdx
// swizzle. Grid 512 % 8 XCDs == 0 -> row-block rb = (bid&7)*64 + (bid>>3):
// 64 consecutive row-blocks per XCD -> shared word-gather rows are filled into
// exactly ONE XCD's L2 (default round-robin duplicates them across all 8).
// Everything else identical to R5.
__global__ __launch_bounds__(256, 2) void slu_main(const float* __restrict__ out_char,
                                                   const float* __restrict__ out_word,
                                                   const int* __restrict__ word_idx,
                                                   const int* __restrict__ is_head,
                                                   const int* __restrict__ valid_mask,
                                                   const __bf16* __restrict__ Wt,
                                                   const float* __restrict__ b_out,
                                                   float* __restrict__ out) {
    // LDS: A[3] @ 0 (3*8192), W[2] @ 24576 (2*10240) = 45056 B
    __shared__ __align__(16) char smem[45056];
    const int tid = threadIdx.x;
    const int wv = tid >> 6;
    const int lane = tid & 63;
    const int l15 = lane & 15;
    const int kgrp = lane >> 4;

    // ---- XCD-aware bijective swizzle (512 blocks = 8 XCDs x 64 chunks) ----
    const int bid = blockIdx.x;
    const int rb = (bid & (NXCD - 1)) * (512 / NXCD) + (bid >> 3);
    const int rowbase = rb * MROWS;

    // ---- A staging (R5 map): thread covers row rloc=(tid>>2), k-sub q=(tid&3) ----
    const int rloc = tid >> 2;
    const int q = tid & 3;
    const int r = rowbase + rloc;
    const int bq = r >> 11;  // T = 2048
    const int widx = word_idx[r];
    const int val = valid_mask[r];
    const float rt = is_head[r] ? 0.88f : 0.70f;
    const float rate = val ? rt : 0.0f;
    const float crate = val ? (1.0f - rt) : 0.0f;
    const float* cptr = out_char + (size_t)r * HH + q * 16;
    const float* wptr = out_word + ((size_t)bq * TT + widx) * HH + q * 16;
    const int asw = (rloc & 7) << 4;
    const int awr0 = (rloc * 128 + q * 32) ^ asw;
    const int awr1 = (rloc * 128 + q * 32 + 16) ^ asw;

    // ---- W staging (R5 map): 640 16B-units/chunk; thread covers tid, tid+256, (tid<128)?tid+512 ----
    const int wn0 = tid >> 3, wsb = tid & 7;
    const __bf16* wgp0 = Wt + (size_t)wn0 * HH + wsb * 8;
    const __bf16* wgp1 = wgp0 + 32 * HH;
    const __bf16* wgp2 = wgp0 + 64 * HH;
    const int wsw = (wn0 & 7) << 4;
    const int wwr0 = (wn0 * 128 + wsb * 16) ^ wsw;
    const int wwr1 = ((wn0 + 32) * 128 + wsb * 16) ^ wsw;
    const int wwr2 = ((wn0 + 64) * 128 + wsb * 16) ^ wsw;
    const bool w3 = (tid < 128);

    // ---- fragment read offsets (swizzle matches writes; row&7 == l15&7 for A and W) ----
    const int fsw = (l15 & 7) << 4;
    const int arow = wv * 16 + l15;
    int aoff[2], woff[2][5];
#pragma unroll
    for (int s = 0; s < 2; ++s) {
        aoff[s] = (arow * 128 + s * 64 + kgrp * 16) ^ fsw;
#pragma unroll
        for (int nt = 0; nt < 5; ++nt)
            woff[s][nt] = ((nt * 16 + l15) * 128 + s * 64 + kgrp * 16) ^ fsw;
    }

    f32x4 acc[5];
#pragma unroll
    for (int nt = 0; nt < 5; ++nt) acc[nt] = (f32x4){0.f, 0.f, 0.f, 0.f};

    float4 ac[4], aw[4];   // held A loads (chunk ch+2)
    bf16x8 wreg0, wreg1, wreg2;

    // ---- prologue: stage chunk 0 directly; prefetch chunk 1 into regs ----
    {
        float4 c0[4], w0[4];
        if (val) {
#pragma unroll
            for (int i = 0; i < 4; ++i) {
                c0[i] = *(const float4*)(cptr + i * 4);
                w0[i] = *(const float4*)(wptr + i * 4);
            }
        }
        bf16x8 wr0 = *(const bf16x8*)(wgp0);
        bf16x8 wr1 = *(const bf16x8*)(wgp1);
        bf16x8 wr2 = w3 ? *(const bf16x8*)(wgp2) : (bf16x8)0;
        bf16x8 f0, f1;
        if (val) {
#pragma unroll
            for (int i = 0; i < 2; ++i) {
                f0[i * 4 + 0] = (__bf16)(w0[i].x * rate + c0[i].x * crate);
                f0[i * 4 + 1] = (__bf16)(w0[i].y * rate + c0[i].y * crate);
                f0[i * 4 + 2] = (__bf16)(w0[i].z * rate + c0[i].z * crate);
                f0[i * 4 + 3] = (__bf16)(w0[i].w * rate + c0[i].w * crate);
                f1[i * 4 + 0] = (__bf16)(w0[i + 2].x * rate + c0[i + 2].x * crate);
                f1[i * 4 + 1] = (__bf16)(w0[i + 2].y * rate + c0[i + 2].y * crate);
                f1[i * 4 + 2] = (__bf16)(w0[i + 2].z * rate + c0[i + 2].z * crate);
                f1[i * 4 + 3] = (__bf16)(w0[i + 2].w * rate + c0[i + 2].w * crate);
            }
        } else {
            f0 = (bf16x8)0; f1 = (bf16x8)0;
        }
        *(bf16x8*)(smem + awr0) = f0;
        *(bf16x8*)(smem + awr1) = f1;
        *(bf16x8*)(smem + 24576 + wwr0) = wr0;
        *(bf16x8*)(smem + 24576 + wwr1) = wr1;
        if (w3) *(bf16x8*)(smem + 24576 + wwr2) = wr2;
        // prefetch chunk 1 into regs
        if (val) {
#pragma unroll
            for (int i = 0; i < 4; ++i) {
                ac[i] = *(const float4*)(cptr + CHK + i * 4);
                aw[i] = *(const float4*)(wptr + CHK + i * 4);
            }
        }
        wreg0 = *(const bf16x8*)(wgp0 + CHK);
        wreg1 = *(const bf16x8*)(wgp1 + CHK);
        wreg2 = w3 ? *(const bf16x8*)(wgp2 + CHK) : (bf16x8)0;
    }
    __syncthreads();

    // ---- main loop ----
    for (int ch = 0; ch < NCH; ++ch) {
        // 1) commit prefetched chunk ch+1 to LDS
        if (ch + 1 < NCH) {
            char* An = smem + ((ch + 1) % 3) * 8192;
            char* Wn = smem + 24576 + ((ch + 1) & 1) * 10240;
            bf16x8 f0, f1;
            if (val) {
#pragma unroll
                for (int i = 0; i < 2; ++i) {
                    f0[i * 4 + 0] = (__bf16)(aw[i].x * rate + ac[i].x * crate);
                    f0[i * 4 + 1] = (__bf16)(aw[i].y * rate + ac[i].y * crate);
                    f0[i * 4 + 2] = (__bf16)(aw[i].z * rate + ac[i].z * crate);
                    f0[i * 4 + 3] = (__bf16)(aw[i].w * rate + ac[i].w * crate);
                    f1[i * 4 + 0] = (__bf16)(aw[i + 2].x * rate + ac[i + 2].x * crate);
                    f1[i * 4 + 1] = (__bf16)(aw[i + 2].y * rate + ac[i + 2].y * crate);
                    f1[i * 4 + 2] = (__bf16)(aw[i + 2].z * rate + ac[i + 2].z * crate);
                    f1[i * 4 + 3] = (__bf16)(aw[i + 2].w * rate + ac[i + 2].w * crate);
                }
            } else {
                f0 = (bf16x8)0; f1 = (bf16x8)0;
            }
            *(bf16x8*)(An + awr0) = f0;
            *(bf16x8*)(An + awr1) = f1;
            *(bf16x8*)(Wn + wwr0) = wreg0;
            *(bf16x8*)(Wn + wwr1) = wreg1;
            if (w3) *(bf16x8*)(Wn + wwr2) = wreg2;
        }
        // 2) issue global loads for chunk ch+2 (held in regs across compute)
        if (ch + 2 < NCH) {
            const int ko = (ch + 2) * CHK;
            if (val) {
#pragma unroll
                for (int i = 0; i < 4; ++i) {
                    ac[i] = *(const float4*)(cptr + ko + i * 4);
                    aw[i] = *(const float4*)(wptr + ko + i * 4);
                }
            }
            wreg0 = *(const bf16x8*)(wgp0 + ko);
            wreg1 = *(const bf16x8*)(wgp1 + ko);
            wreg2 = w3 ? *(const bf16x8*)(wgp2 + ko) : (bf16x8)0;
        }
        // 3) compute chunk ch
        const char* Ab = smem + (ch % 3) * 8192;
        const char* Wb = smem + 24576 + (ch & 1) * 10240;
#pragma unroll
        for (int s = 0; s < 2; ++s) {
            bf16x8 a = *(const bf16x8*)(Ab + aoff[s]);
#pragma unroll
            for (int nt = 0; nt < 5; ++nt) {
                bf16x8 bw = *(const bf16x8*)(Wb + woff[s][nt]);
                acc[nt] = __builtin_amdgcn_mfma_f32_16x16x32_bf16(a, bw, acc[nt], 0, 0, 0);
            }
        }
        __syncthreads();
    }

    // ---- epilogue: C/D col = lane&15, row = (lane>>4)*4 + reg  [verified R2-R11] ----
    const int orow = rowbase + wv * 16 + kgrp * 4;
#pragma unroll
    for (int nt = 0; nt < 5; ++nt) {
        const int col = nt * 16 + l15;
        if (col < NTAGS) {
            const float bias = b_out[col];
#pragma unroll
            for (int i = 0; i < 4; ++i) {
                out[(size_t)(orow + i) * NTAGS + col] = acc[nt][i] + bias;
            }
        }
    }
}

extern "C" void kernel_launch(void* const* d_in, const int* in_sizes, int n_in,
                              void* d_out, int out_size, void* d_ws, size_t ws_size,
                              hipStream_t stream) {
    const float* out_char = (const float*)d_in[0];
    const float* out_word = (const float*)d_in[1];
    const int* word_idx = (const int*)d_in[2];
    const int* is_head = (const int*)d_in[3];
    const int* valid_mask = (const int*)d_in[4];
    const float* W_out = (const float*)d_in[5];
    const float* b_out = (const float*)d_in[6];
    float* out = (float*)d_out;
    __bf16* Wt = (__bf16*)d_ws;  // 80*1024*2 = 160 KB

    prep_w_kernel<<<HH / 64, 256, 0, stream>>>(W_out, Wt);

    const int rows = 16 * TT;  // B*T = 32768
    slu_main<<<rows / MROWS, THREADS, 0, stream>>>(out_char, out_word, word_idx, is_head,
                                                   valid_mask, Wt, b_out, out);
}